// Round 6
// baseline (52.599 us; speedup 1.0000x reference)
//
#include <hip/hip_runtime.h>
#include <cstdint>

static constexpr int Bc = 32, Tc = 128, Fc = 32, Hc = 4, HDc = 16, RKc = 16;
static constexpr int Nc = Tc * Fc;  // 4096
static constexpr int WS36 = 36;     // row-major [*][32] padded stride
static constexpr int TS = 132;      // transposed [32][128] padded stride

__device__ __forceinline__ uint32_t rotl32(uint32_t v, int r) {
  return (v << r) | (v >> (32 - r));
}

__device__ __forceinline__ void threefry2x32(uint32_t k0, uint32_t k1,
                                             uint32_t& x0, uint32_t& x1) {
  uint32_t k2 = k0 ^ k1 ^ 0x1BD11BDAu;
  x0 += k0; x1 += k1;
#define TF_R(r) { x0 += x1; x1 = rotl32(x1, (r)); x1 ^= x0; }
  TF_R(13) TF_R(15) TF_R(26) TF_R(6)
  x0 += k1; x1 += k2 + 1u;
  TF_R(17) TF_R(29) TF_R(16) TF_R(24)
  x0 += k2; x1 += k0 + 2u;
  TF_R(13) TF_R(15) TF_R(26) TF_R(6)
  x0 += k0; x1 += k1 + 3u;
  TF_R(17) TF_R(29) TF_R(16) TF_R(24)
  x0 += k1; x1 += k2 + 4u;
  TF_R(13) TF_R(15) TF_R(26) TF_R(6)
  x0 += k2; x1 += k0 + 5u;
#undef TF_R
}

__device__ __forceinline__ float erfinv_f32(float x) {
  float w = -logf((1.0f - x) * (1.0f + x));
  float p;
  if (w < 5.0f) {
    w -= 2.5f;
    p = 2.81022636e-08f;
    p = fmaf(p, w, 3.43273939e-07f);
    p = fmaf(p, w, -3.5233877e-06f);
    p = fmaf(p, w, -4.39150654e-06f);
    p = fmaf(p, w, 0.00021858087f);
    p = fmaf(p, w, -0.00125372503f);
    p = fmaf(p, w, -0.00417768164f);
    p = fmaf(p, w, 0.246640727f);
    p = fmaf(p, w, 1.50140941f);
  } else {
    w = sqrtf(w) - 3.0f;
    p = -0.000200214257f;
    p = fmaf(p, w, 0.000100950558f);
    p = fmaf(p, w, 0.00134934322f);
    p = fmaf(p, w, -0.00367342844f);
    p = fmaf(p, w, 0.00573950773f);
    p = fmaf(p, w, -0.0076224613f);
    p = fmaf(p, w, 0.00943887047f);
    p = fmaf(p, w, 1.00167406f);
    p = fmaf(p, w, 2.83297682f);
  }
  return p * x;
}

__device__ __forceinline__ float jax_normal_from_bits(uint32_t bits) {
  const float lo = -0.99999994f;
  float f = __uint_as_float((bits >> 9) | 0x3f800000u) - 1.0f;
  float u = fmaxf(lo, f * 2.0f + lo);
  return 1.41421354f * erfinv_f32(u);
}

// ---------------------------------------------------------------------------
// K1: scores + row softmax + threshold + dense ta + per-row CSR.
// grid (h, t1chunk=8), 256 threads. (unchanged from round 5 — proven)
// ---------------------------------------------------------------------------
__global__ __launch_bounds__(256)
void score_kernel(const float* __restrict__ x, const float* __restrict__ weight,
                  const float* __restrict__ tqg, const float* __restrict__ tkg,
                  float* __restrict__ ws_ta, float* __restrict__ ws_rs,
                  int* __restrict__ ws_rowcnt, int* __restrict__ ws_cols,
                  float* __restrict__ ws_vals) {
  const int h = blockIdx.x, t1c = blockIdx.y;
  const int tid = (int)threadIdx.x;
  __shared__ float kS[Bc][Tc];
  __shared__ float qS[Bc][16];
  __shared__ float wqv[Fc], wkv[Fc];

  if (tid < Fc) {
    const float* W0 = weight + h * (Fc * HDc);
    float aq = 0.f, ak = 0.f;
    for (int d = 0; d < HDc; ++d) {
      float w0 = W0[tid * HDc + d];
      aq += w0 * tqg[h * HDc + d];
      ak += w0 * tkg[h * HDc + d];
    }
    wqv[tid] = aq; wkv[tid] = ak;
  }
  __syncthreads();

  for (int i = tid; i < Bc * Tc; i += 256) {
    const float4* xr = (const float4*)(x + (size_t)i * Fc);
    float ak = 0.f;
#pragma unroll
    for (int j = 0; j < 8; ++j) {
      float4 v = xr[j];
      ak += v.x * wkv[4*j] + v.y * wkv[4*j+1] + v.z * wkv[4*j+2] + v.w * wkv[4*j+3];
    }
    kS[i >> 7][i & 127] = ak;
  }
  for (int i = tid; i < Bc * 16; i += 256) {
    int b = i >> 4, tt = i & 15;
    const float4* xr = (const float4*)(x + ((size_t)b * Tc + 16 * t1c + tt) * Fc);
    float aq = 0.f;
#pragma unroll
    for (int j = 0; j < 8; ++j) {
      float4 v = xr[j];
      aq += v.x * wqv[4*j] + v.y * wqv[4*j+1] + v.z * wqv[4*j+2] + v.w * wqv[4*j+3];
    }
    qS[b][tt] = aq;
  }
  __syncthreads();

  const int t1l = tid >> 4, t2g = tid & 15, gl = tid & 15;
  const int gt1 = 16 * t1c + t1l;
  float acc[8] = {};
  for (int b = 0; b < Bc; ++b) {
    float q = qS[b][t1l];
    float4 k0 = *(const float4*)&kS[b][8 * t2g];
    float4 k1 = *(const float4*)&kS[b][8 * t2g + 4];
    float kv[8] = {k0.x, k0.y, k0.z, k0.w, k1.x, k1.y, k1.z, k1.w};
#pragma unroll
    for (int j = 0; j < 8; ++j) {
      float s = q + kv[j];
      acc[j] += fmaxf(s, 0.2f * s);
    }
  }
#pragma unroll
  for (int j = 0; j < 8; ++j) acc[j] *= (1.0f / 32.0f);

  float m = acc[0];
#pragma unroll
  for (int j = 1; j < 8; ++j) m = fmaxf(m, acc[j]);
  for (int o = 8; o > 0; o >>= 1) m = fmaxf(m, __shfl_xor(m, o, 16));
  float e[8], se = 0.f;
#pragma unroll
  for (int j = 0; j < 8; ++j) { e[j] = expf(acc[j] - m); se += e[j]; }
  for (int o = 8; o > 0; o >>= 1) se += __shfl_xor(se, o, 16);
  float p[8]; int keep[8]; int cnt = 0; float rs = 0.f;
#pragma unroll
  for (int j = 0; j < 8; ++j) {
    float pv = e[j] / se;
    int col = 8 * t2g + j;
    int k = (pv > 0.01f) && (col != gt1);
    p[j] = k ? pv : 0.f;
    keep[j] = k;
    cnt += k;
    rs += p[j];
  }
  for (int o = 8; o > 0; o >>= 1) rs += __shfl_xor(rs, o, 16);

  float* tar = ws_ta + (size_t)h * (Tc * Tc) + (size_t)gt1 * Tc + 8 * t2g;
  *(float4*)tar       = make_float4(p[0], p[1], p[2], p[3]);
  *(float4*)(tar + 4) = make_float4(p[4], p[5], p[6], p[7]);

  int ci = cnt;
  for (int o = 1; o < 16; o <<= 1) {
    int u = __shfl_up(ci, o, 16);
    if (gl >= o) ci += u;
  }
  int excl = ci - cnt;
  int total = __shfl(ci, 15, 16);
  if (gl == 0) {
    ws_rowcnt[h * Tc + gt1] = total;
    ws_rs[h * Tc + gt1] = rs;
  }
  int off = gt1 * Tc + excl;
#pragma unroll
  for (int j = 0; j < 8; ++j) {
    if (keep[j]) {
      ws_cols[h * (Tc * Tc) + off] = 8 * t2g + j;
      ws_vals[h * (Tc * Tc) + off] = p[j];
      ++off;
    }
  }
}

// ---------------------------------------------------------------------------
// K2: fused head+conv. grid (b, h) = 128 blocks, 256 threads.
// Per block: fa, flag, PRNG v0, sparse power iteration -> sn, then
// G = (c-1)X - c*s.*(ta^T@Z + Z@fa + Z),  out = X@W0 + G@W1 + bias.
// Redundant per-head work (fa/pi) is ~1-2 us and fully parallel; this
// removes one dispatch (~5-10 us) and the 4-block serialization.
// ---------------------------------------------------------------------------
__global__ __launch_bounds__(256)
void fused_kernel(const float* __restrict__ x, const float* __restrict__ weight,
                  const float* __restrict__ bias, const float* __restrict__ ffg,
                  const float* __restrict__ ws_ta, const float* __restrict__ ws_rs,
                  const int* __restrict__ ws_rowcnt, const int* __restrict__ ws_cols,
                  const float* __restrict__ ws_vals, float* __restrict__ out) {
  const int b = blockIdx.x, h = blockIdx.y;
  const int tid = (int)threadIdx.x;
  const int lane = tid & 63, wv = tid >> 6;

  __shared__ __align__(16) float taS[Tc * Tc];      // 64 KB (staged only if flag)
  __shared__ __align__(16) float bufRow[Tc * WS36]; // pi wL -> conv Zs
  __shared__ __align__(16) float bufT[Fc * TS];     // pi wTL -> conv ZT
  __shared__ __align__(16) float XT[Fc * TS];
  __shared__ __align__(16) float GT[Fc * TS];
  __shared__ __align__(16) float faS[Fc * WS36];    // fa row-major [f1][f2]
  __shared__ __align__(16) float faTS[Fc * WS36];   // fa transposed [f2][f1]
  __shared__ __align__(16) float W0s[Fc * HDc];
  __shared__ __align__(16) float W1s[Fc * HDc];
  __shared__ float rsT[Tc], rsF[Fc], red[4];
  __shared__ float bcastS;
  __shared__ int rcS[Tc], flagS;

  if (tid < Tc) {
    rsT[tid] = ws_rs[h * Tc + tid];
    rcS[tid] = ws_rowcnt[h * Tc + tid];
  }
  for (int i = tid; i < Fc * HDc; i += 256) {
    W0s[i] = weight[h * (Fc * HDc) + i];
    W1s[i] = weight[(Hc + h) * (Fc * HDc) + i];
  }
  __syncthreads();

  if (tid < 64) {
    int nz = (rcS[tid] != 0) || (rcS[tid + 64] != 0);
    unsigned long long bal = __ballot(nz);
    if (tid == 0) flagS = (bal != 0ull) ? 1 : 0;
  }

  // fa = threshold(softmax(leaky_relu(U V^T), axis=1)); both orientations + rsF
  for (int j2 = tid; j2 < Fc * Fc; j2 += 256) {
    const float* U = ffg + h * (2 * Fc * RKc);
    const float* V = U + Fc * RKc;
    int f1 = j2 >> 5, f2 = j2 & 31;
    float acc = 0.f;
    for (int r = 0; r < RKc; ++r) acc += U[f1 * RKc + r] * V[f2 * RKc + r];
    float val = fmaxf(acc, 0.2f * acc);
    float m = val;
    for (int o = 16; o > 0; o >>= 1) m = fmaxf(m, __shfl_xor(m, o, 32));
    float e = expf(val - m), se = e;
    for (int o = 16; o > 0; o >>= 1) se += __shfl_xor(se, o, 32);
    float pv = e / se;
    pv = (pv > 0.01f && f1 != f2) ? pv : 0.f;
    faS[f1 * WS36 + f2] = pv;
    faTS[f2 * WS36 + f1] = pv;
    float rsum = pv;
    for (int o = 16; o > 0; o >>= 1) rsum += __shfl_xor(rsum, o, 32);
    if (f2 == 0) rsF[f1] = rsum;
  }
  __syncthreads();  // flagS, fa, rsF visible

  // early taS staging (overlaps with pi compute; consumed only in G phase)
  if (flagS) {
    const float4* taG = (const float4*)(ws_ta + (size_t)h * (Tc * Tc));
    for (int i = tid; i < Tc * Tc / 4; i += 256) ((float4*)taS)[i] = taG[i];
  }

  // ---- power iteration. thread = rows {tq, tq+64}, f = f0..f0+8 (wave-uniform f0)
  const int tq = tid & 63, fb = tid >> 6, f0 = 8 * fb;
  float v_reg[2][8], s_reg[2][8], nv[2][8];
#pragma unroll
  for (int r = 0; r < 2; ++r) {
    float rrow = rsT[tq + 64 * r];
#pragma unroll
    for (int j = 0; j < 8; ++j)
      s_reg[r][j] = 1.0f / sqrtf(rrow + rsF[f0 + j] + 1.0f + 1e-10f);
  }
  {
    uint32_t fk0 = 0u, fk1 = (uint32_t)h;
    threefry2x32(0u, 42u, fk0, fk1);
#pragma unroll
    for (int j = 0; j < 8; ++j) {
      int l = tq * Fc + f0 + j;  // < 2048 always (tq < 64)
      uint32_t c0 = (uint32_t)l, c1 = (uint32_t)(l + 2048);
      threefry2x32(fk0, fk1, c0, c1);
      v_reg[0][j] = jax_normal_from_bits(c0);   // element (tq, f)
      v_reg[1][j] = jax_normal_from_bits(c1);   // element (tq+64, f)
    }
  }
#pragma unroll
  for (int r = 0; r < 2; ++r) {
    int t = tq + 64 * r;
    float w[8];
#pragma unroll
    for (int j = 0; j < 8; ++j) w[j] = s_reg[r][j] * v_reg[r][j];
    *(float4*)&bufRow[t * WS36 + f0]     = make_float4(w[0], w[1], w[2], w[3]);
    *(float4*)&bufRow[t * WS36 + f0 + 4] = make_float4(w[4], w[5], w[6], w[7]);
#pragma unroll
    for (int j = 0; j < 8; ++j) bufT[(f0 + j) * TS + t] = w[j];
  }
  __syncthreads();

  const int csrBase = h * (Tc * Tc);
  for (int it = 0; it < 4; ++it) {
    float acc[2][8] = {};
    // M1 (sparse CSR, global; ascending col -> deterministic)
#pragma unroll
    for (int r = 0; r < 2; ++r) {
      int t = tq + 64 * r;
      int bse = csrBase + t * Tc, cnt = rcS[t];
      for (int e = 0; e < cnt; ++e) {
        int col = ws_cols[bse + e];
        float val = ws_vals[bse + e];
        float4 w4a = *(const float4*)&bufRow[col * WS36 + f0];
        float4 w4b = *(const float4*)&bufRow[col * WS36 + f0 + 4];
        acc[r][0] += val * w4a.x; acc[r][1] += val * w4a.y;
        acc[r][2] += val * w4a.z; acc[r][3] += val * w4a.w;
        acc[r][4] += val * w4b.x; acc[r][5] += val * w4b.y;
        acc[r][6] += val * w4b.z; acc[r][7] += val * w4b.w;
      }
    }
    // M2: sum_f2 fa[f][f2] * w[t][f2]  (faTS broadcast, bufT lane-consecutive)
    for (int f2 = 0; f2 < Fc; ++f2) {
      float4 fa0 = *(const float4*)&faTS[f2 * WS36 + f0];
      float4 fa1 = *(const float4*)&faTS[f2 * WS36 + f0 + 4];
      float w0 = bufT[f2 * TS + tq];
      float w1 = bufT[f2 * TS + tq + 64];
      acc[0][0] += w0 * fa0.x; acc[0][1] += w0 * fa0.y;
      acc[0][2] += w0 * fa0.z; acc[0][3] += w0 * fa0.w;
      acc[0][4] += w0 * fa1.x; acc[0][5] += w0 * fa1.y;
      acc[0][6] += w0 * fa1.z; acc[0][7] += w0 * fa1.w;
      acc[1][0] += w1 * fa0.x; acc[1][1] += w1 * fa0.y;
      acc[1][2] += w1 * fa0.z; acc[1][3] += w1 * fa0.w;
      acc[1][4] += w1 * fa1.x; acc[1][5] += w1 * fa1.y;
      acc[1][6] += w1 * fa1.z; acc[1][7] += w1 * fa1.w;
    }
    float partv = 0.f;
#pragma unroll
    for (int r = 0; r < 2; ++r)
#pragma unroll
      for (int j = 0; j < 8; ++j) {
        float a = acc[r][j] + s_reg[r][j] * v_reg[r][j];  // + identity part
        float nvv = v_reg[r][j] - s_reg[r][j] * a;        // (Lv)
        nv[r][j] = nvv;
        partv += (it < 3) ? nvv * nvv : v_reg[r][j] * nvv;
      }
    for (int o = 32; o > 0; o >>= 1) partv += __shfl_down(partv, o, 64);
    if (lane == 0) red[wv] = partv;
    __syncthreads();
    if (tid == 0) bcastS = red[0] + red[1] + red[2] + red[3];
    __syncthreads();
    if (it < 3) {
      float inv = 1.0f / (sqrtf(bcastS) + 1e-10f);
#pragma unroll
      for (int r = 0; r < 2; ++r) {
        int t = tq + 64 * r;
        float w[8];
#pragma unroll
        for (int j = 0; j < 8; ++j) {
          v_reg[r][j] = nv[r][j] * inv;
          w[j] = s_reg[r][j] * v_reg[r][j];
        }
        *(float4*)&bufRow[t * WS36 + f0]     = make_float4(w[0], w[1], w[2], w[3]);
        *(float4*)&bufRow[t * WS36 + f0 + 4] = make_float4(w[4], w[5], w[6], w[7]);
#pragma unroll
        for (int j = 0; j < 8; ++j) bufT[(f0 + j) * TS + t] = w[j];
      }
      __syncthreads();
    }
  }
  // bcastS now holds the Rayleigh quotient; all pi reads of buffers are done.
  const float sn = fmaxf(fabsf(bcastS), 1.0f);
  const float csn = 2.0f / sn;
  const float cm1 = csn - 1.0f;

  // ---- stage x: XT, Zs(=bufRow), ZT(=bufT)
  const float* xb = x + (size_t)b * Nc;
  for (int i = tid; i < Nc / 4; i += 256) {
    int row = i >> 3, c4 = i & 7;
    float4 xv = *(const float4*)&xb[row * Fc + 4 * c4];
    float rrow = rsT[row];
    float s0 = 1.0f / sqrtf(rrow + rsF[4 * c4 + 0] + 1.0f + 1e-10f);
    float s1 = 1.0f / sqrtf(rrow + rsF[4 * c4 + 1] + 1.0f + 1e-10f);
    float s2 = 1.0f / sqrtf(rrow + rsF[4 * c4 + 2] + 1.0f + 1e-10f);
    float s3 = 1.0f / sqrtf(rrow + rsF[4 * c4 + 3] + 1.0f + 1e-10f);
    float4 zv = make_float4(xv.x * s0, xv.y * s1, xv.z * s2, xv.w * s3);
    *(float4*)&bufRow[row * WS36 + 4 * c4] = zv;
    XT[(4 * c4 + 0) * TS + row] = xv.x; bufT[(4 * c4 + 0) * TS + row] = zv.x;
    XT[(4 * c4 + 1) * TS + row] = xv.y; bufT[(4 * c4 + 1) * TS + row] = zv.y;
    XT[(4 * c4 + 2) * TS + row] = xv.z; bufT[(4 * c4 + 2) * TS + row] = zv.z;
    XT[(4 * c4 + 3) * TS + row] = xv.w; bufT[(4 * c4 + 3) * TS + row] = zv.w;
  }
  __syncthreads();

  // ---- G phase: lanes = t (conflict-free), f0c = 8*(tid>>6) wave-uniform
  {
    const int tt = tid & 63, f0c = 8 * (tid >> 6);
    float acc[2][8] = {};
    if (flagS) {
      for (int k = 0; k < Tc; ++k) {
        float ta0 = taS[k * Tc + tt];
        float ta1 = taS[k * Tc + tt + 64];
        float4 z0 = *(const float4*)&bufRow[k * WS36 + f0c];      // broadcast
        float4 z1 = *(const float4*)&bufRow[k * WS36 + f0c + 4];  // broadcast
        acc[0][0] += ta0 * z0.x; acc[0][1] += ta0 * z0.y;
        acc[0][2] += ta0 * z0.z; acc[0][3] += ta0 * z0.w;
        acc[0][4] += ta0 * z1.x; acc[0][5] += ta0 * z1.y;
        acc[0][6] += ta0 * z1.z; acc[0][7] += ta0 * z1.w;
        acc[1][0] += ta1 * z0.x; acc[1][1] += ta1 * z0.y;
        acc[1][2] += ta1 * z0.z; acc[1][3] += ta1 * z0.w;
        acc[1][4] += ta1 * z1.x; acc[1][5] += ta1 * z1.y;
        acc[1][6] += ta1 * z1.z; acc[1][7] += ta1 * z1.w;
      }
    }
    for (int f2 = 0; f2 < Fc; ++f2) {
      float4 fa0 = *(const float4*)&faS[f2 * WS36 + f0c];      // broadcast
      float4 fa1 = *(const float4*)&faS[f2 * WS36 + f0c + 4];  // broadcast
      float zt0 = bufT[f2 * TS + tt];
      float zt1 = bufT[f2 * TS + tt + 64];
      acc[0][0] += zt0 * fa0.x; acc[0][1] += zt0 * fa0.y;
      acc[0][2] += zt0 * fa0.z; acc[0][3] += zt0 * fa0.w;
      acc[0][4] += zt0 * fa1.x; acc[0][5] += zt0 * fa1.y;
      acc[0][6] += zt0 * fa1.z; acc[0][7] += zt0 * fa1.w;
      acc[1][0] += zt1 * fa0.x; acc[1][1] += zt1 * fa0.y;
      acc[1][2] += zt1 * fa0.z; acc[1][3] += zt1 * fa0.w;
      acc[1][4] += zt1 * fa1.x; acc[1][5] += zt1 * fa1.y;
      acc[1][6] += zt1 * fa1.z; acc[1][7] += zt1 * fa1.w;
    }
#pragma unroll
    for (int r = 0; r < 2; ++r) {
      int t = tt + 64 * r;
      float rrow = rsT[t];
#pragma unroll
      for (int j = 0; j < 8; ++j) {
        int f = f0c + j;
        float xv = XT[f * TS + t];
        float zv = bufT[f * TS + t];
        float sv = 1.0f / sqrtf(rrow + rsF[f] + 1.0f + 1e-10f);
        GT[f * TS + t] = cm1 * xv - csn * sv * (acc[r][j] + zv);
      }
    }
  }
  __syncthreads();

  // ---- out GEMM: lanes = t, hd-block = 4*(tid>>6) wave-uniform
  {
    const int tt = tid & 63, hb = tid >> 6;
    float acc2[2][4] = {};
    for (int f = 0; f < Fc; ++f) {
      float4 w0 = *(const float4*)&W0s[f * HDc + 4 * hb];  // broadcast
      float4 w1 = *(const float4*)&W1s[f * HDc + 4 * hb];  // broadcast
      float x0 = XT[f * TS + tt], x1 = XT[f * TS + tt + 64];
      float g0 = GT[f * TS + tt], g1 = GT[f * TS + tt + 64];
      acc2[0][0] += x0 * w0.x + g0 * w1.x;
      acc2[0][1] += x0 * w0.y + g0 * w1.y;
      acc2[0][2] += x0 * w0.z + g0 * w1.z;
      acc2[0][3] += x0 * w0.w + g0 * w1.w;
      acc2[1][0] += x1 * w0.x + g1 * w1.x;
      acc2[1][1] += x1 * w0.y + g1 * w1.y;
      acc2[1][2] += x1 * w0.z + g1 * w1.z;
      acc2[1][3] += x1 * w0.w + g1 * w1.w;
    }
    float4 bv = *(const float4*)&bias[h * HDc + 4 * hb];
#pragma unroll
    for (int r = 0; r < 2; ++r) {
      int t = tt + 64 * r;
      float4 o4 = make_float4(acc2[r][0] + bv.x, acc2[r][1] + bv.y,
                              acc2[r][2] + bv.z, acc2[r][3] + bv.w);
      *(float4*)&out[((size_t)b * Tc + t) * (Hc * HDc) + h * HDc + 4 * hb] = o4;
    }
  }
}

extern "C" void kernel_launch(void* const* d_in, const int* in_sizes, int n_in,
                              void* d_out, int out_size, void* d_ws, size_t ws_size,
                              hipStream_t stream) {
  const float* x      = (const float*)d_in[0];
  const float* weight = (const float*)d_in[1];
  const float* bias   = (const float*)d_in[2];
  const float* tqg    = (const float*)d_in[3];
  const float* tkg    = (const float*)d_in[4];
  const float* ffg    = (const float*)d_in[5];
  float* out = (float*)d_out;

  float* ws = (float*)d_ws;
  float* ws_ta     = ws;                    // 4*16384 = 65536
  float* ws_rs     = ws + 65536;            // 512
  int*   ws_rowcnt = (int*)(ws + 66048);    // 512
  int*   ws_cols   = (int*)(ws + 66560);    // 65536
  float* ws_vals   = ws + 132096;           // 65536

  score_kernel<<<dim3(Hc, 8), dim3(256), 0, stream>>>(
      x, weight, tqg, tkg, ws_ta, ws_rs, ws_rowcnt, ws_cols, ws_vals);
  fused_kernel<<<dim3(Bc, Hc), dim3(256), 0, stream>>>(
      x, weight, bias, ffg, ws_ta, ws_rs, ws_rowcnt, ws_cols, ws_vals, out);
}

// Round 7
// 48.516 us; speedup vs baseline: 1.0842x; 1.0842x over previous
//
#include <hip/hip_runtime.h>
#include <cstdint>

static constexpr int Bc = 32, Tc = 128, Fc = 32, Hc = 4, HDc = 16, RKc = 16;
static constexpr int Nc = Tc * Fc;  // 4096
static constexpr int WS36 = 36;     // row-major [*][32] padded stride
static constexpr int TS = 132;      // transposed [32][128] padded stride

__device__ __forceinline__ uint32_t rotl32(uint32_t v, int r) {
  return (v << r) | (v >> (32 - r));
}

__device__ __forceinline__ void threefry2x32(uint32_t k0, uint32_t k1,
                                             uint32_t& x0, uint32_t& x1) {
  uint32_t k2 = k0 ^ k1 ^ 0x1BD11BDAu;
  x0 += k0; x1 += k1;
#define TF_R(r) { x0 += x1; x1 = rotl32(x1, (r)); x1 ^= x0; }
  TF_R(13) TF_R(15) TF_R(26) TF_R(6)
  x0 += k1; x1 += k2 + 1u;
  TF_R(17) TF_R(29) TF_R(16) TF_R(24)
  x0 += k2; x1 += k0 + 2u;
  TF_R(13) TF_R(15) TF_R(26) TF_R(6)
  x0 += k0; x1 += k1 + 3u;
  TF_R(17) TF_R(29) TF_R(16) TF_R(24)
  x0 += k1; x1 += k2 + 4u;
  TF_R(13) TF_R(15) TF_R(26) TF_R(6)
  x0 += k2; x1 += k0 + 5u;
#undef TF_R
}

__device__ __forceinline__ float erfinv_f32(float x) {
  float w = -logf((1.0f - x) * (1.0f + x));
  float p;
  if (w < 5.0f) {
    w -= 2.5f;
    p = 2.81022636e-08f;
    p = fmaf(p, w, 3.43273939e-07f);
    p = fmaf(p, w, -3.5233877e-06f);
    p = fmaf(p, w, -4.39150654e-06f);
    p = fmaf(p, w, 0.00021858087f);
    p = fmaf(p, w, -0.00125372503f);
    p = fmaf(p, w, -0.00417768164f);
    p = fmaf(p, w, 0.246640727f);
    p = fmaf(p, w, 1.50140941f);
  } else {
    w = sqrtf(w) - 3.0f;
    p = -0.000200214257f;
    p = fmaf(p, w, 0.000100950558f);
    p = fmaf(p, w, 0.00134934322f);
    p = fmaf(p, w, -0.00367342844f);
    p = fmaf(p, w, 0.00573950773f);
    p = fmaf(p, w, -0.0076224613f);
    p = fmaf(p, w, 0.00943887047f);
    p = fmaf(p, w, 1.00167406f);
    p = fmaf(p, w, 2.83297682f);
  }
  return p * x;
}

__device__ __forceinline__ float jax_normal_from_bits(uint32_t bits) {
  const float lo = -0.99999994f;
  float f = __uint_as_float((bits >> 9) | 0x3f800000u) - 1.0f;
  float u = fmaxf(lo, f * 2.0f + lo);
  return 1.41421354f * erfinv_f32(u);
}

// ---------------------------------------------------------------------------
// K1: scores + row softmax + threshold + dense ta + per-row CSR.
// grid (h, t1chunk=8), 256 threads. (unchanged — proven)
// ---------------------------------------------------------------------------
__global__ __launch_bounds__(256)
void score_kernel(const float* __restrict__ x, const float* __restrict__ weight,
                  const float* __restrict__ tqg, const float* __restrict__ tkg,
                  float* __restrict__ ws_ta, float* __restrict__ ws_rs,
                  int* __restrict__ ws_rowcnt, int* __restrict__ ws_cols,
                  float* __restrict__ ws_vals) {
  const int h = blockIdx.x, t1c = blockIdx.y;
  const int tid = (int)threadIdx.x;
  __shared__ float kS[Bc][Tc];
  __shared__ float qS[Bc][16];
  __shared__ float wqv[Fc], wkv[Fc];

  if (tid < Fc) {
    const float* W0 = weight + h * (Fc * HDc);
    float aq = 0.f, ak = 0.f;
    for (int d = 0; d < HDc; ++d) {
      float w0 = W0[tid * HDc + d];
      aq += w0 * tqg[h * HDc + d];
      ak += w0 * tkg[h * HDc + d];
    }
    wqv[tid] = aq; wkv[tid] = ak;
  }
  __syncthreads();

  for (int i = tid; i < Bc * Tc; i += 256) {
    const float4* xr = (const float4*)(x + (size_t)i * Fc);
    float ak = 0.f;
#pragma unroll
    for (int j = 0; j < 8; ++j) {
      float4 v = xr[j];
      ak += v.x * wkv[4*j] + v.y * wkv[4*j+1] + v.z * wkv[4*j+2] + v.w * wkv[4*j+3];
    }
    kS[i >> 7][i & 127] = ak;
  }
  for (int i = tid; i < Bc * 16; i += 256) {
    int b = i >> 4, tt = i & 15;
    const float4* xr = (const float4*)(x + ((size_t)b * Tc + 16 * t1c + tt) * Fc);
    float aq = 0.f;
#pragma unroll
    for (int j = 0; j < 8; ++j) {
      float4 v = xr[j];
      aq += v.x * wqv[4*j] + v.y * wqv[4*j+1] + v.z * wqv[4*j+2] + v.w * wqv[4*j+3];
    }
    qS[b][tt] = aq;
  }
  __syncthreads();

  const int t1l = tid >> 4, t2g = tid & 15, gl = tid & 15;
  const int gt1 = 16 * t1c + t1l;
  float acc[8] = {};
  for (int b = 0; b < Bc; ++b) {
    float q = qS[b][t1l];
    float4 k0 = *(const float4*)&kS[b][8 * t2g];
    float4 k1 = *(const float4*)&kS[b][8 * t2g + 4];
    float kv[8] = {k0.x, k0.y, k0.z, k0.w, k1.x, k1.y, k1.z, k1.w};
#pragma unroll
    for (int j = 0; j < 8; ++j) {
      float s = q + kv[j];
      acc[j] += fmaxf(s, 0.2f * s);
    }
  }
#pragma unroll
  for (int j = 0; j < 8; ++j) acc[j] *= (1.0f / 32.0f);

  float m = acc[0];
#pragma unroll
  for (int j = 1; j < 8; ++j) m = fmaxf(m, acc[j]);
  for (int o = 8; o > 0; o >>= 1) m = fmaxf(m, __shfl_xor(m, o, 16));
  float e[8], se = 0.f;
#pragma unroll
  for (int j = 0; j < 8; ++j) { e[j] = expf(acc[j] - m); se += e[j]; }
  for (int o = 8; o > 0; o >>= 1) se += __shfl_xor(se, o, 16);
  float p[8]; int keep[8]; int cnt = 0; float rs = 0.f;
#pragma unroll
  for (int j = 0; j < 8; ++j) {
    float pv = e[j] / se;
    int col = 8 * t2g + j;
    int k = (pv > 0.01f) && (col != gt1);
    p[j] = k ? pv : 0.f;
    keep[j] = k;
    cnt += k;
    rs += p[j];
  }
  for (int o = 8; o > 0; o >>= 1) rs += __shfl_xor(rs, o, 16);

  float* tar = ws_ta + (size_t)h * (Tc * Tc) + (size_t)gt1 * Tc + 8 * t2g;
  *(float4*)tar       = make_float4(p[0], p[1], p[2], p[3]);
  *(float4*)(tar + 4) = make_float4(p[4], p[5], p[6], p[7]);

  int ci = cnt;
  for (int o = 1; o < 16; o <<= 1) {
    int u = __shfl_up(ci, o, 16);
    if (gl >= o) ci += u;
  }
  int excl = ci - cnt;
  int total = __shfl(ci, 15, 16);
  if (gl == 0) {
    ws_rowcnt[h * Tc + gt1] = total;
    ws_rs[h * Tc + gt1] = rs;
  }
  int off = gt1 * Tc + excl;
#pragma unroll
  for (int j = 0; j < 8; ++j) {
    if (keep[j]) {
      ws_cols[h * (Tc * Tc) + off] = 8 * t2g + j;
      ws_vals[h * (Tc * Tc) + off] = p[j];
      ++off;
    }
  }
}

// ---------------------------------------------------------------------------
// K2: fused head+conv, 512 threads (8 waves -> 2/SIMD for latency hiding).
// grid (b, h) = 128 blocks. LDS ~67 KB (no taS; GT reuses bufRow).
// thread map (pi/G/out): t = tid&127 (lane-consecutive), group = tid>>7
// ---------------------------------------------------------------------------
__global__ __launch_bounds__(512)
void fused_kernel(const float* __restrict__ x, const float* __restrict__ weight,
                  const float* __restrict__ bias, const float* __restrict__ ffg,
                  const float* __restrict__ ws_ta, const float* __restrict__ ws_rs,
                  const int* __restrict__ ws_rowcnt, const int* __restrict__ ws_cols,
                  const float* __restrict__ ws_vals, float* __restrict__ out) {
  const int b = blockIdx.x, h = blockIdx.y;
  const int tid = (int)threadIdx.x;
  const int lane = tid & 63, wv = tid >> 6;

  __shared__ __align__(16) float bufRow[Tc * WS36]; // pi wL -> Zs -> GT(Fc*TS<=4608)
  __shared__ __align__(16) float bufT[Fc * TS];     // pi wT -> ZT
  __shared__ __align__(16) float XT[Fc * TS];
  __shared__ __align__(16) float faS[Fc * WS36];    // fa[f1][f2]
  __shared__ __align__(16) float faTS[Fc * WS36];   // faT[f2][f1]
  __shared__ __align__(16) float W0s[Fc * HDc];
  __shared__ __align__(16) float W1s[Fc * HDc];
  __shared__ float rsT[Tc], rsF[Fc], red[8];
  __shared__ float bcastS;
  __shared__ int rcS[Tc], flagS;

  if (tid < Tc) {
    rsT[tid] = ws_rs[h * Tc + tid];
    rcS[tid] = ws_rowcnt[h * Tc + tid];
  }
  for (int i = tid; i < Fc * HDc; i += 512) {
    W0s[i] = weight[h * (Fc * HDc) + i];
    W1s[i] = weight[(Hc + h) * (Fc * HDc) + i];
  }
  __syncthreads();

  if (tid < 64) {
    int nz = (rcS[tid] != 0) || (rcS[tid + 64] != 0);
    unsigned long long bal = __ballot(nz);
    if (tid == 0) flagS = (bal != 0ull) ? 1 : 0;
  }

  // fa = threshold(softmax(leaky_relu(U V^T), axis=1)); both orientations + rsF
  for (int j2 = tid; j2 < Fc * Fc; j2 += 512) {
    const float* U = ffg + h * (2 * Fc * RKc);
    const float* V = U + Fc * RKc;
    int f1 = j2 >> 5, f2 = j2 & 31;
    float acc = 0.f;
    for (int r = 0; r < RKc; ++r) acc += U[f1 * RKc + r] * V[f2 * RKc + r];
    float val = fmaxf(acc, 0.2f * acc);
    float m = val;
    for (int o = 16; o > 0; o >>= 1) m = fmaxf(m, __shfl_xor(m, o, 32));
    float e = expf(val - m), se = e;
    for (int o = 16; o > 0; o >>= 1) se += __shfl_xor(se, o, 32);
    float pv = e / se;
    pv = (pv > 0.01f && f1 != f2) ? pv : 0.f;
    faS[f1 * WS36 + f2] = pv;
    faTS[f2 * WS36 + f1] = pv;
    float rsum = pv;
    for (int o = 16; o > 0; o >>= 1) rsum += __shfl_xor(rsum, o, 32);
    if (f2 == 0) rsF[f1] = rsum;
  }
  __syncthreads();  // flagS, fa, rsF visible

  // ---- power iteration: thread = (t = tid&127, f = f0..f0+8), f0 wave-uniform
  const int t = tid & 127, f0 = 8 * (tid >> 7);
  float v_reg[8], s_reg[8], nv[8];
  {
    float rrow = rsT[t];
#pragma unroll
    for (int j = 0; j < 8; ++j)
      s_reg[j] = 1.0f / sqrtf(rrow + rsF[f0 + j] + 1.0f + 1e-10f);
  }
  {
    uint32_t fk0 = 0u, fk1 = (uint32_t)h;
    threefry2x32(0u, 42u, fk0, fk1);
#pragma unroll
    for (int j = 0; j < 8; ++j) {
      int l = t * Fc + f0 + j;           // 0..4095
      int pr = l & 2047;
      uint32_t c0 = (uint32_t)pr, c1 = (uint32_t)(pr + 2048);
      threefry2x32(fk0, fk1, c0, c1);
      v_reg[j] = jax_normal_from_bits(l < 2048 ? c0 : c1);
    }
  }
  {
    float w[8];
#pragma unroll
    for (int j = 0; j < 8; ++j) w[j] = s_reg[j] * v_reg[j];
    *(float4*)&bufRow[t * WS36 + f0]     = make_float4(w[0], w[1], w[2], w[3]);
    *(float4*)&bufRow[t * WS36 + f0 + 4] = make_float4(w[4], w[5], w[6], w[7]);
#pragma unroll
    for (int j = 0; j < 8; ++j) bufT[(f0 + j) * TS + t] = w[j];
  }
  __syncthreads();

  const int csrBase = h * (Tc * Tc);
  const int myCnt = rcS[t];
  for (int it = 0; it < 4; ++it) {
    float acc[8] = {};
    // M1 (sparse CSR; cnt==0 for the expected input)
    {
      int bse = csrBase + t * Tc;
      for (int e = 0; e < myCnt; ++e) {
        int col = ws_cols[bse + e];
        float val = ws_vals[bse + e];
        float4 w4a = *(const float4*)&bufRow[col * WS36 + f0];
        float4 w4b = *(const float4*)&bufRow[col * WS36 + f0 + 4];
        acc[0] += val * w4a.x; acc[1] += val * w4a.y;
        acc[2] += val * w4a.z; acc[3] += val * w4a.w;
        acc[4] += val * w4b.x; acc[5] += val * w4b.y;
        acc[6] += val * w4b.z; acc[7] += val * w4b.w;
      }
    }
    // M2: sum_f2 fa[f][f2] * w[t][f2]
    for (int f2 = 0; f2 < Fc; ++f2) {
      float4 fa0 = *(const float4*)&faTS[f2 * WS36 + f0];      // broadcast
      float4 fa1 = *(const float4*)&faTS[f2 * WS36 + f0 + 4];  // broadcast
      float w0 = bufT[f2 * TS + t];                            // lane-consecutive
      acc[0] += w0 * fa0.x; acc[1] += w0 * fa0.y;
      acc[2] += w0 * fa0.z; acc[3] += w0 * fa0.w;
      acc[4] += w0 * fa1.x; acc[5] += w0 * fa1.y;
      acc[6] += w0 * fa1.z; acc[7] += w0 * fa1.w;
    }
    float partv = 0.f;
#pragma unroll
    for (int j = 0; j < 8; ++j) {
      float a = acc[j] + s_reg[j] * v_reg[j];   // + identity part
      float nvv = v_reg[j] - s_reg[j] * a;      // (Lv)
      nv[j] = nvv;
      partv += (it < 3) ? nvv * nvv : v_reg[j] * nvv;
    }
    for (int o = 32; o > 0; o >>= 1) partv += __shfl_down(partv, o, 64);
    if (lane == 0) red[wv] = partv;
    __syncthreads();
    if (tid == 0) {
      float s2 = 0.f;
      for (int i2 = 0; i2 < 8; ++i2) s2 += red[i2];
      bcastS = s2;
    }
    __syncthreads();
    if (it < 3) {
      float inv = 1.0f / (sqrtf(bcastS) + 1e-10f);
      float w[8];
#pragma unroll
      for (int j = 0; j < 8; ++j) {
        v_reg[j] = nv[j] * inv;
        w[j] = s_reg[j] * v_reg[j];
      }
      *(float4*)&bufRow[t * WS36 + f0]     = make_float4(w[0], w[1], w[2], w[3]);
      *(float4*)&bufRow[t * WS36 + f0 + 4] = make_float4(w[4], w[5], w[6], w[7]);
#pragma unroll
      for (int j = 0; j < 8; ++j) bufT[(f0 + j) * TS + t] = w[j];
      __syncthreads();
    }
  }
  const float sn = fmaxf(fabsf(bcastS), 1.0f);
  const float csn = 2.0f / sn;
  const float cm1 = csn - 1.0f;

  // ---- stage x: Zs(=bufRow), ZT(=bufT), XT  (pi reads complete)
  const float* xb = x + (size_t)b * Nc;
  for (int i = tid; i < Nc / 4; i += 512) {
    int row = i >> 3, c4 = i & 7;
    float4 xv = *(const float4*)&xb[row * Fc + 4 * c4];
    float rrow = rsT[row];
    float s0 = 1.0f / sqrtf(rrow + rsF[4 * c4 + 0] + 1.0f + 1e-10f);
    float s1 = 1.0f / sqrtf(rrow + rsF[4 * c4 + 1] + 1.0f + 1e-10f);
    float s2 = 1.0f / sqrtf(rrow + rsF[4 * c4 + 2] + 1.0f + 1e-10f);
    float s3 = 1.0f / sqrtf(rrow + rsF[4 * c4 + 3] + 1.0f + 1e-10f);
    float4 zv = make_float4(xv.x * s0, xv.y * s1, xv.z * s2, xv.w * s3);
    *(float4*)&bufRow[row * WS36 + 4 * c4] = zv;
    XT[(4 * c4 + 0) * TS + row] = xv.x; bufT[(4 * c4 + 0) * TS + row] = zv.x;
    XT[(4 * c4 + 1) * TS + row] = xv.y; bufT[(4 * c4 + 1) * TS + row] = zv.y;
    XT[(4 * c4 + 2) * TS + row] = xv.z; bufT[(4 * c4 + 2) * TS + row] = zv.z;
    XT[(4 * c4 + 3) * TS + row] = xv.w; bufT[(4 * c4 + 3) * TS + row] = zv.w;
  }
  __syncthreads();

  // ---- G phase: t = tid&127, f0 wave-uniform; G kept in regs, then GT->bufRow
  float greg[8];
  {
    float acc[8] = {};
    if (flagS) {  // rare path: dense ta from global (L2-resident)
      const float* taG = ws_ta + (size_t)h * (Tc * Tc);
      for (int k = 0; k < Tc; ++k) {
        float ta0 = taG[k * Tc + t];                             // coalesced
        float4 z0 = *(const float4*)&bufRow[k * WS36 + f0];      // broadcast
        float4 z1 = *(const float4*)&bufRow[k * WS36 + f0 + 4];  // broadcast
        acc[0] += ta0 * z0.x; acc[1] += ta0 * z0.y;
        acc[2] += ta0 * z0.z; acc[3] += ta0 * z0.w;
        acc[4] += ta0 * z1.x; acc[5] += ta0 * z1.y;
        acc[6] += ta0 * z1.z; acc[7] += ta0 * z1.w;
      }
    }
    for (int f2 = 0; f2 < Fc; ++f2) {
      float4 fa0 = *(const float4*)&faS[f2 * WS36 + f0];      // broadcast
      float4 fa1 = *(const float4*)&faS[f2 * WS36 + f0 + 4];  // broadcast
      float zt0 = bufT[f2 * TS + t];                          // lane-consecutive
      acc[0] += zt0 * fa0.x; acc[1] += zt0 * fa0.y;
      acc[2] += zt0 * fa0.z; acc[3] += zt0 * fa0.w;
      acc[4] += zt0 * fa1.x; acc[5] += zt0 * fa1.y;
      acc[6] += zt0 * fa1.z; acc[7] += zt0 * fa1.w;
    }
    float rrow = rsT[t];
#pragma unroll
    for (int j = 0; j < 8; ++j) {
      int f = f0 + j;
      float xv = XT[f * TS + t];
      float zv = bufT[f * TS + t];
      float sv = 1.0f / sqrtf(rrow + rsF[f] + 1.0f + 1e-10f);
      greg[j] = cm1 * xv - csn * sv * (acc[j] + zv);
    }
  }
  __syncthreads();  // all reads of bufRow (Zs) complete
#pragma unroll
  for (int j = 0; j < 8; ++j) bufRow[(f0 + j) * TS + t] = greg[j];  // GT
  __syncthreads();

  // ---- out GEMM: t = tid&127, hd-block = 4*(tid>>7) wave-uniform
  {
    const int hb = tid >> 7;
    float acc2[4] = {};
    for (int f = 0; f < Fc; ++f) {
      float4 w0 = *(const float4*)&W0s[f * HDc + 4 * hb];  // broadcast
      float4 w1 = *(const float4*)&W1s[f * HDc + 4 * hb];  // broadcast
      float xv = XT[f * TS + t];
      float gv = bufRow[f * TS + t];
      acc2[0] += xv * w0.x + gv * w1.x;
      acc2[1] += xv * w0.y + gv * w1.y;
      acc2[2] += xv * w0.z + gv * w1.z;
      acc2[3] += xv * w0.w + gv * w1.w;
    }
    float4 bv = *(const float4*)&bias[h * HDc + 4 * hb];
    float4 o4 = make_float4(acc2[0] + bv.x, acc2[1] + bv.y,
                            acc2[2] + bv.z, acc2[3] + bv.w);
    *(float4*)&out[((size_t)b * Tc + t) * (Hc * HDc) + h * HDc + 4 * hb] = o4;
  }
}

extern "C" void kernel_launch(void* const* d_in, const int* in_sizes, int n_in,
                              void* d_out, int out_size, void* d_ws, size_t ws_size,
                              hipStream_t stream) {
  const float* x      = (const float*)d_in[0];
  const float* weight = (const float*)d_in[1];
  const float* bias   = (const float*)d_in[2];
  const float* tqg    = (const float*)d_in[3];
  const float* tkg    = (const float*)d_in[4];
  const float* ffg    = (const float*)d_in[5];
  float* out = (float*)d_out;

  float* ws = (float*)d_ws;
  float* ws_ta     = ws;                    // 4*16384 = 65536
  float* ws_rs     = ws + 65536;            // 512
  int*   ws_rowcnt = (int*)(ws + 66048);    // 512
  int*   ws_cols   = (int*)(ws + 66560);    // 65536
  float* ws_vals   = ws + 132096;           // 65536

  score_kernel<<<dim3(Hc, 8), dim3(256), 0, stream>>>(
      x, weight, tqg, tkg, ws_ta, ws_rs, ws_rowcnt, ws_cols, ws_vals);
  fused_kernel<<<dim3(Bc, Hc), dim3(512), 0, stream>>>(
      x, weight, bias, ffg, ws_ta, ws_rs, ws_rowcnt, ws_cols, ws_vals, out);
}

// Round 8
// 45.478 us; speedup vs baseline: 1.1566x; 1.0668x over previous
//
#include <hip/hip_runtime.h>
#include <cstdint>

static constexpr int Bc = 32, Tc = 128, Fc = 32, Hc = 4, HDc = 16, RKc = 16;
static constexpr int Nc = Tc * Fc;  // 4096
static constexpr int WS36 = 36;     // row-major [*][32] padded stride
static constexpr int TS = 132;      // transposed [32][128] padded stride

__device__ __forceinline__ uint32_t rotl32(uint32_t v, int r) {
  return (v << r) | (v >> (32 - r));
}

__device__ __forceinline__ void threefry2x32(uint32_t k0, uint32_t k1,
                                             uint32_t& x0, uint32_t& x1) {
  uint32_t k2 = k0 ^ k1 ^ 0x1BD11BDAu;
  x0 += k0; x1 += k1;
#define TF_R(r) { x0 += x1; x1 = rotl32(x1, (r)); x1 ^= x0; }
  TF_R(13) TF_R(15) TF_R(26) TF_R(6)
  x0 += k1; x1 += k2 + 1u;
  TF_R(17) TF_R(29) TF_R(16) TF_R(24)
  x0 += k2; x1 += k0 + 2u;
  TF_R(13) TF_R(15) TF_R(26) TF_R(6)
  x0 += k0; x1 += k1 + 3u;
  TF_R(17) TF_R(29) TF_R(16) TF_R(24)
  x0 += k1; x1 += k2 + 4u;
  TF_R(13) TF_R(15) TF_R(26) TF_R(6)
  x0 += k2; x1 += k0 + 5u;
#undef TF_R
}

// XLA ErfInv32; __logf (v_log_f32) — rel err ~1e-6, harmless for v0/sn.
__device__ __forceinline__ float erfinv_f32(float x) {
  float w = -__logf((1.0f - x) * (1.0f + x));
  float p;
  if (w < 5.0f) {
    w -= 2.5f;
    p = 2.81022636e-08f;
    p = fmaf(p, w, 3.43273939e-07f);
    p = fmaf(p, w, -3.5233877e-06f);
    p = fmaf(p, w, -4.39150654e-06f);
    p = fmaf(p, w, 0.00021858087f);
    p = fmaf(p, w, -0.00125372503f);
    p = fmaf(p, w, -0.00417768164f);
    p = fmaf(p, w, 0.246640727f);
    p = fmaf(p, w, 1.50140941f);
  } else {
    w = sqrtf(w) - 3.0f;
    p = -0.000200214257f;
    p = fmaf(p, w, 0.000100950558f);
    p = fmaf(p, w, 0.00134934322f);
    p = fmaf(p, w, -0.00367342844f);
    p = fmaf(p, w, 0.00573950773f);
    p = fmaf(p, w, -0.0076224613f);
    p = fmaf(p, w, 0.00943887047f);
    p = fmaf(p, w, 1.00167406f);
    p = fmaf(p, w, 2.83297682f);
  }
  return p * x;
}

__device__ __forceinline__ float jax_normal_from_bits(uint32_t bits) {
  const float lo = -0.99999994f;
  float f = __uint_as_float((bits >> 9) | 0x3f800000u) - 1.0f;
  float u = fmaxf(lo, f * 2.0f + lo);
  return 1.41421354f * erfinv_f32(u);
}

// ---------------------------------------------------------------------------
// K1: scores + row softmax + threshold + dense ta + per-row CSR.
// grid (h, chunk=8 of 16 rows), 512 threads (2 waves/SIMD for latency hiding).
// Thread = (t1l = tid>>5 in 0..15, t2q = tid&31 -> 4 cols each).
// ---------------------------------------------------------------------------
__global__ __launch_bounds__(512)
void score_kernel(const float* __restrict__ x, const float* __restrict__ weight,
                  const float* __restrict__ tqg, const float* __restrict__ tkg,
                  float* __restrict__ ws_ta, float* __restrict__ ws_rs,
                  int* __restrict__ ws_rowcnt, int* __restrict__ ws_cols,
                  float* __restrict__ ws_vals) {
  const int h = blockIdx.x, chunk = blockIdx.y;
  const int tid = (int)threadIdx.x;
  __shared__ float kS[Bc][Tc];
  __shared__ float qS[Bc][16];
  __shared__ float wqv[Fc], wkv[Fc];

  if (tid < Fc) {
    const float* W0 = weight + h * (Fc * HDc);
    float aq = 0.f, ak = 0.f;
    for (int d = 0; d < HDc; ++d) {
      float w0 = W0[tid * HDc + d];
      aq += w0 * tqg[h * HDc + d];
      ak += w0 * tkg[h * HDc + d];
    }
    wqv[tid] = aq; wkv[tid] = ak;
  }
  __syncthreads();

  // k for all (b,t): 8 rows/thread
  for (int i = tid; i < Bc * Tc; i += 512) {
    const float4* xr = (const float4*)(x + (size_t)i * Fc);
    float ak = 0.f;
#pragma unroll
    for (int j = 0; j < 8; ++j) {
      float4 v = xr[j];
      ak += v.x * wkv[4*j] + v.y * wkv[4*j+1] + v.z * wkv[4*j+2] + v.w * wkv[4*j+3];
    }
    kS[i >> 7][i & 127] = ak;
  }
  // q for this chunk's 16 rows x 32 batches: 1 row/thread
  {
    int b = tid >> 4, tt = tid & 15;
    const float4* xr = (const float4*)(x + ((size_t)b * Tc + 16 * chunk + tt) * Fc);
    float aq = 0.f;
#pragma unroll
    for (int j = 0; j < 8; ++j) {
      float4 v = xr[j];
      aq += v.x * wqv[4*j] + v.y * wqv[4*j+1] + v.z * wqv[4*j+2] + v.w * wqv[4*j+3];
    }
    qS[b][tt] = aq;
  }
  __syncthreads();

  const int t1l = tid >> 5, t2q = tid & 31;
  const int gt1 = 16 * chunk + t1l;
  float acc[4] = {};
  for (int b = 0; b < Bc; ++b) {
    float q = qS[b][t1l];
    float4 k4 = *(const float4*)&kS[b][4 * t2q];
    float kv[4] = {k4.x, k4.y, k4.z, k4.w};
#pragma unroll
    for (int j = 0; j < 4; ++j) {
      float s = q + kv[j];
      acc[j] += fmaxf(s, 0.2f * s);
    }
  }
#pragma unroll
  for (int j = 0; j < 4; ++j) acc[j] *= (1.0f / 32.0f);

  // softmax over 128 cols held by 32 lanes (4/lane)
  float m = fmaxf(fmaxf(acc[0], acc[1]), fmaxf(acc[2], acc[3]));
  for (int o = 16; o > 0; o >>= 1) m = fmaxf(m, __shfl_xor(m, o, 32));
  float e[4], se = 0.f;
#pragma unroll
  for (int j = 0; j < 4; ++j) { e[j] = expf(acc[j] - m); se += e[j]; }
  for (int o = 16; o > 0; o >>= 1) se += __shfl_xor(se, o, 32);
  float p[4]; int keep[4]; int cnt = 0; float rs = 0.f;
#pragma unroll
  for (int j = 0; j < 4; ++j) {
    float pv = e[j] / se;
    int col = 4 * t2q + j;
    int k = (pv > 0.01f) && (col != gt1);
    p[j] = k ? pv : 0.f;
    keep[j] = k;
    cnt += k;
    rs += p[j];
  }
  for (int o = 16; o > 0; o >>= 1) rs += __shfl_xor(rs, o, 32);

  // dense thresholded row (row-major, coalesced)
  float* tar = ws_ta + (size_t)h * (Tc * Tc) + (size_t)gt1 * Tc + 4 * t2q;
  *(float4*)tar = make_float4(p[0], p[1], p[2], p[3]);

  // per-row CSR segment at base gt1*Tc (ascending col, deterministic)
  int ci = cnt;
  for (int o = 1; o < 32; o <<= 1) {
    int u = __shfl_up(ci, o, 32);
    if (t2q >= o) ci += u;
  }
  int excl = ci - cnt;
  int total = __shfl(ci, 31, 32);
  if (t2q == 0) {
    ws_rowcnt[h * Tc + gt1] = total;
    ws_rs[h * Tc + gt1] = rs;
  }
  int off = gt1 * Tc + excl;
#pragma unroll
  for (int j = 0; j < 4; ++j) {
    if (keep[j]) {
      ws_cols[h * (Tc * Tc) + off] = 4 * t2q + j;
      ws_vals[h * (Tc * Tc) + off] = p[j];
      ++off;
    }
  }
}

// ---------------------------------------------------------------------------
// K2: fused head+conv, 512 threads. grid (b, h) = 128 blocks.
// pi map: (t = tid&63, f0 = 4*(tid>>6)), rows {t, t+64} -> 4 threefry/thread.
// G/out map: (t = tid&127, group = tid>>7). 2 barriers per pi iteration.
// ---------------------------------------------------------------------------
__global__ __launch_bounds__(512)
void fused_kernel(const float* __restrict__ x, const float* __restrict__ weight,
                  const float* __restrict__ bias, const float* __restrict__ ffg,
                  const float* __restrict__ ws_ta, const float* __restrict__ ws_rs,
                  const int* __restrict__ ws_rowcnt, const int* __restrict__ ws_cols,
                  const float* __restrict__ ws_vals, float* __restrict__ out) {
  const int b = blockIdx.x, h = blockIdx.y;
  const int tid = (int)threadIdx.x;
  const int lane = tid & 63, wv = tid >> 6;

  __shared__ __align__(16) float bufRow[Tc * WS36]; // pi w -> Zs -> GT
  __shared__ __align__(16) float bufT[Fc * TS];     // pi wT -> ZT
  __shared__ __align__(16) float XT[Fc * TS];
  __shared__ __align__(16) float faS[Fc * WS36];    // fa[f1][f2]
  __shared__ __align__(16) float faTS[Fc * WS36];   // faT[f2][f1]
  __shared__ __align__(16) float W0s[Fc * HDc];
  __shared__ __align__(16) float W1s[Fc * HDc];
  __shared__ float rsT[Tc], rsF[Fc], red[8];
  __shared__ int rcS[Tc], flagS;

  if (tid < Tc) {
    rsT[tid] = ws_rs[h * Tc + tid];
    rcS[tid] = ws_rowcnt[h * Tc + tid];
  }
  for (int i = tid; i < Fc * HDc; i += 512) {
    W0s[i] = weight[h * (Fc * HDc) + i];
    W1s[i] = weight[(Hc + h) * (Fc * HDc) + i];
  }
  __syncthreads();

  if (tid < 64) {
    int nz = (rcS[tid] != 0) || (rcS[tid + 64] != 0);
    unsigned long long bal = __ballot(nz);
    if (tid == 0) flagS = (bal != 0ull) ? 1 : 0;
  }

  // fa = threshold(softmax(leaky_relu(U V^T), axis=1)); both orientations + rsF
  for (int j2 = tid; j2 < Fc * Fc; j2 += 512) {
    const float* U = ffg + h * (2 * Fc * RKc);
    const float* V = U + Fc * RKc;
    int f1 = j2 >> 5, f2 = j2 & 31;
    float acc = 0.f;
    for (int r = 0; r < RKc; ++r) acc += U[f1 * RKc + r] * V[f2 * RKc + r];
    float val = fmaxf(acc, 0.2f * acc);
    float m = val;
    for (int o = 16; o > 0; o >>= 1) m = fmaxf(m, __shfl_xor(m, o, 32));
    float e = expf(val - m), se = e;
    for (int o = 16; o > 0; o >>= 1) se += __shfl_xor(se, o, 32);
    float pv = e / se;
    pv = (pv > 0.01f && f1 != f2) ? pv : 0.f;
    faS[f1 * WS36 + f2] = pv;
    faTS[f2 * WS36 + f1] = pv;
    float rsum = pv;
    for (int o = 16; o > 0; o >>= 1) rsum += __shfl_xor(rsum, o, 32);
    if (f2 == 0) rsF[f1] = rsum;
  }
  __syncthreads();  // flagS, fa, rsF visible

  // ---- power iteration: rows {t, t+64}, cols f0..f0+4 (f0 wave-uniform)
  const int t = tid & 63, f0 = 4 * (tid >> 6);
  float v_reg[2][4], s_reg[2][4], nv[2][4];
#pragma unroll
  for (int r = 0; r < 2; ++r) {
    float rrow = rsT[t + 64 * r];
#pragma unroll
    for (int j = 0; j < 4; ++j)
      s_reg[r][j] = 1.0f / sqrtf(rrow + rsF[f0 + j] + 1.0f + 1e-10f);
  }
  {
    uint32_t fk0 = 0u, fk1 = (uint32_t)h;
    threefry2x32(0u, 42u, fk0, fk1);
#pragma unroll
    for (int j = 0; j < 4; ++j) {
      int l = t * Fc + f0 + j;  // < 2048 (t < 64)
      uint32_t c0 = (uint32_t)l, c1 = (uint32_t)(l + 2048);
      threefry2x32(fk0, fk1, c0, c1);
      v_reg[0][j] = jax_normal_from_bits(c0);   // (t, f)
      v_reg[1][j] = jax_normal_from_bits(c1);   // (t+64, f)
    }
  }
#pragma unroll
  for (int r = 0; r < 2; ++r) {
    int row = t + 64 * r;
    float w[4];
#pragma unroll
    for (int j = 0; j < 4; ++j) w[j] = s_reg[r][j] * v_reg[r][j];
    *(float4*)&bufRow[row * WS36 + f0] = make_float4(w[0], w[1], w[2], w[3]);
#pragma unroll
    for (int j = 0; j < 4; ++j) bufT[(f0 + j) * TS + row] = w[j];
  }
  __syncthreads();

  const int csrBase = h * (Tc * Tc);
  float snv = 1.0f;
  for (int it = 0; it < 4; ++it) {
    float acc[2][4] = {};
    if (flagS) {  // M1 (sparse CSR) — skipped when ta == 0
#pragma unroll
      for (int r = 0; r < 2; ++r) {
        int row = t + 64 * r;
        int bse = csrBase + row * Tc, cnt = rcS[row];
        for (int e = 0; e < cnt; ++e) {
          int col = ws_cols[bse + e];
          float val = ws_vals[bse + e];
          float4 w4 = *(const float4*)&bufRow[col * WS36 + f0];
          acc[r][0] += val * w4.x; acc[r][1] += val * w4.y;
          acc[r][2] += val * w4.z; acc[r][3] += val * w4.w;
        }
      }
    }
    // M2: sum_f2 fa[f][f2] * w[row][f2]
    for (int f2 = 0; f2 < Fc; ++f2) {
      float4 fav = *(const float4*)&faTS[f2 * WS36 + f0];  // broadcast
      float w0 = bufT[f2 * TS + t];                        // lane-consecutive
      float w1 = bufT[f2 * TS + t + 64];
      acc[0][0] += w0 * fav.x; acc[0][1] += w0 * fav.y;
      acc[0][2] += w0 * fav.z; acc[0][3] += w0 * fav.w;
      acc[1][0] += w1 * fav.x; acc[1][1] += w1 * fav.y;
      acc[1][2] += w1 * fav.z; acc[1][3] += w1 * fav.w;
    }
    float partv = 0.f;
#pragma unroll
    for (int r = 0; r < 2; ++r)
#pragma unroll
      for (int j = 0; j < 4; ++j) {
        float a = acc[r][j] + s_reg[r][j] * v_reg[r][j];  // + identity
        float nvv = v_reg[r][j] - s_reg[r][j] * a;        // (Lv)
        nv[r][j] = nvv;
        partv += (it < 3) ? nvv * nvv : v_reg[r][j] * nvv;
      }
    for (int o = 32; o > 0; o >>= 1) partv += __shfl_down(partv, o, 64);
    if (lane == 0) red[wv] = partv;
    __syncthreads();                         // barrier 1
    float total = 0.f;
#pragma unroll
    for (int i2 = 0; i2 < 8; ++i2) total += red[i2];  // redundant sum, broadcast reads
    if (it < 3) {
      float inv = 1.0f / (sqrtf(total) + 1e-10f);
#pragma unroll
      for (int r = 0; r < 2; ++r) {
        int row = t + 64 * r;
        float w[4];
#pragma unroll
        for (int j = 0; j < 4; ++j) {
          v_reg[r][j] = nv[r][j] * inv;
          w[j] = s_reg[r][j] * v_reg[r][j];
        }
        *(float4*)&bufRow[row * WS36 + f0] = make_float4(w[0], w[1], w[2], w[3]);
#pragma unroll
        for (int j = 0; j < 4; ++j) bufT[(f0 + j) * TS + row] = w[j];
      }
      __syncthreads();                       // barrier 2
    } else {
      snv = fmaxf(fabsf(total), 1.0f);
    }
  }
  const float csn = 2.0f / snv;
  const float cm1 = csn - 1.0f;

  // ---- stage x: Zs(=bufRow), ZT(=bufT), XT   (all pi reads complete)
  const float* xb = x + (size_t)b * Nc;
  for (int i = tid; i < Nc / 4; i += 512) {
    int row = i >> 3, c4 = i & 7;
    float4 xv = *(const float4*)&xb[row * Fc + 4 * c4];
    float rrow = rsT[row];
    float s0 = 1.0f / sqrtf(rrow + rsF[4 * c4 + 0] + 1.0f + 1e-10f);
    float s1 = 1.0f / sqrtf(rrow + rsF[4 * c4 + 1] + 1.0f + 1e-10f);
    float s2 = 1.0f / sqrtf(rrow + rsF[4 * c4 + 2] + 1.0f + 1e-10f);
    float s3 = 1.0f / sqrtf(rrow + rsF[4 * c4 + 3] + 1.0f + 1e-10f);
    float4 zv = make_float4(xv.x * s0, xv.y * s1, xv.z * s2, xv.w * s3);
    *(float4*)&bufRow[row * WS36 + 4 * c4] = zv;
    XT[(4 * c4 + 0) * TS + row] = xv.x; bufT[(4 * c4 + 0) * TS + row] = zv.x;
    XT[(4 * c4 + 1) * TS + row] = xv.y; bufT[(4 * c4 + 1) * TS + row] = zv.y;
    XT[(4 * c4 + 2) * TS + row] = xv.z; bufT[(4 * c4 + 2) * TS + row] = zv.z;
    XT[(4 * c4 + 3) * TS + row] = xv.w; bufT[(4 * c4 + 3) * TS + row] = zv.w;
  }
  __syncthreads();

  // ---- G phase: t2 = tid&127, fg = 8*(tid>>7) wave-uniform; G in regs -> GT
  const int t2 = tid & 127, fg = 8 * (tid >> 7);
  float greg[8];
  {
    float acc[8] = {};
    if (flagS) {  // rare path: dense ta from global (L2-resident)
      const float* taG = ws_ta + (size_t)h * (Tc * Tc);
      for (int k = 0; k < Tc; ++k) {
        float ta0 = taG[k * Tc + t2];                            // coalesced
        float4 z0 = *(const float4*)&bufRow[k * WS36 + fg];      // broadcast
        float4 z1 = *(const float4*)&bufRow[k * WS36 + fg + 4];  // broadcast
        acc[0] += ta0 * z0.x; acc[1] += ta0 * z0.y;
        acc[2] += ta0 * z0.z; acc[3] += ta0 * z0.w;
        acc[4] += ta0 * z1.x; acc[5] += ta0 * z1.y;
        acc[6] += ta0 * z1.z; acc[7] += ta0 * z1.w;
      }
    }
    for (int f2 = 0; f2 < Fc; ++f2) {
      float4 fa0 = *(const float4*)&faS[f2 * WS36 + fg];      // broadcast
      float4 fa1 = *(const float4*)&faS[f2 * WS36 + fg + 4];  // broadcast
      float zt0 = bufT[f2 * TS + t2];                         // lane-consecutive
      acc[0] += zt0 * fa0.x; acc[1] += zt0 * fa0.y;
      acc[2] += zt0 * fa0.z; acc[3] += zt0 * fa0.w;
      acc[4] += zt0 * fa1.x; acc[5] += zt0 * fa1.y;
      acc[6] += zt0 * fa1.z; acc[7] += zt0 * fa1.w;
    }
    float rrow = rsT[t2];
#pragma unroll
    for (int j = 0; j < 8; ++j) {
      int f = fg + j;
      float xv = XT[f * TS + t2];
      float zv = bufT[f * TS + t2];
      float sv = 1.0f / sqrtf(rrow + rsF[f] + 1.0f + 1e-10f);
      greg[j] = cm1 * xv - csn * sv * (acc[j] + zv);
    }
  }
  __syncthreads();  // all reads of bufRow (Zs) complete
#pragma unroll
  for (int j = 0; j < 8; ++j) bufRow[(fg + j) * TS + t2] = greg[j];  // GT
  __syncthreads();

  // ---- out GEMM: t2 lanes, hd-block = 4*(tid>>7) wave-uniform
  {
    const int hb = tid >> 7;
    float acc2[4] = {};
    for (int f = 0; f < Fc; ++f) {
      float4 w0 = *(const float4*)&W0s[f * HDc + 4 * hb];  // broadcast
      float4 w1 = *(const float4*)&W1s[f * HDc + 4 * hb];  // broadcast
      float xv = XT[f * TS + t2];
      float gv = bufRow[f * TS + t2];
      acc2[0] += xv * w0.x + gv * w1.x;
      acc2[1] += xv * w0.y + gv * w1.y;
      acc2[2] += xv * w0.z + gv * w1.z;
      acc2[3] += xv * w0.w + gv * w1.w;
    }
    float4 bv = *(const float4*)&bias[h * HDc + 4 * hb];
    float4 o4 = make_float4(acc2[0] + bv.x, acc2[1] + bv.y,
                            acc2[2] + bv.z, acc2[3] + bv.w);
    *(float4*)&out[((size_t)b * Tc + t2) * (Hc * HDc) + h * HDc + 4 * hb] = o4;
  }
}

extern "C" void kernel_launch(void* const* d_in, const int* in_sizes, int n_in,
                              void* d_out, int out_size, void* d_ws, size_t ws_size,
                              hipStream_t stream) {
  const float* x      = (const float*)d_in[0];
  const float* weight = (const float*)d_in[1];
  const float* bias   = (const float*)d_in[2];
  const float* tqg    = (const float*)d_in[3];
  const float* tkg    = (const float*)d_in[4];
  const float* ffg    = (const float*)d_in[5];
  float* out = (float*)d_out;

  float* ws = (float*)d_ws;
  float* ws_ta     = ws;                    // 4*16384 = 65536
  float* ws_rs     = ws + 65536;            // 512
  int*   ws_rowcnt = (int*)(ws + 66048);    // 512
  int*   ws_cols   = (int*)(ws + 66560);    // 65536
  float* ws_vals   = ws + 132096;           // 65536

  score_kernel<<<dim3(Hc, 8), dim3(512), 0, stream>>>(
      x, weight, tqg, tkg, ws_ta, ws_rs, ws_rowcnt, ws_cols, ws_vals);
  fused_kernel<<<dim3(Bc, Hc), dim3(512), 0, stream>>>(
      x, weight, bias, ffg, ws_ta, ws_rs, ws_rowcnt, ws_cols, ws_vals, out);
}